// Round 3
// baseline (829.049 us; speedup 1.0000x reference)
//
#include <hip/hip_runtime.h>
#include <hip/hip_bf16.h>

#define B_   128
#define C_   2048
#define S_   196
#define HID_ 1024
#define T_   20

typedef __attribute__((ext_vector_type(8))) short s16x8;   // 8 bf16 (4 VGPRs)
typedef __attribute__((ext_vector_type(4))) short s16x4;   // 4 bf16
typedef __attribute__((ext_vector_type(4))) float f32x4_t; // MFMA 16x16 acc
typedef __attribute__((ext_vector_type(4))) unsigned short us4;

__device__ __forceinline__ float fast_tanh(float x) {
  float e = __expf(2.f * x);
  return 1.f - 2.f / (e + 1.f);
}
__device__ __forceinline__ unsigned short f2bf(float x) {
  __hip_bfloat16 h = __float2bfloat16(x);
  return *reinterpret_cast<unsigned short*>(&h);
}
__device__ __forceinline__ float bf2f(short s) {
  unsigned int b = ((unsigned int)(unsigned short)s) << 16;
  return __builtin_bit_cast(float, b);
}
__device__ __forceinline__ void gl_lds16(const short* g, short* l) {
  __builtin_amdgcn_global_load_lds(
      (const __attribute__((address_space(1))) void*)g,
      (__attribute__((address_space(3))) void*)l, 16, 0, 0);
}

// ---------------- fp32 -> bf16 weight convert ----------------
__global__ void cvt_k(const float* __restrict__ in, __hip_bfloat16* __restrict__ out, int n) {
  int i = (blockIdx.x * 256 + threadIdx.x) * 4;
  if (i >= n) return;
  float4 v = *(const float4*)(in + i);
  out[i + 0] = __float2bfloat16(v.x);
  out[i + 1] = __float2bfloat16(v.y);
  out[i + 2] = __float2bfloat16(v.z);
  out[i + 3] = __float2bfloat16(v.w);
}

// ---------------- v_i [b,c,s] fp32 -> viT [b,s,c] bf16 ----------------
__global__ void transpose_k(const float* __restrict__ src, __hip_bfloat16* __restrict__ dst) {
  __shared__ float tile[32][65];
  int b  = blockIdx.z;
  int c0 = blockIdx.x * 64;
  int s0 = blockIdx.y * 32;
  int t  = threadIdx.x;
  int cl = t >> 3, sq = t & 7;
  const float* sp = src + ((size_t)b * C_ + c0) * S_ + s0;
  #pragma unroll
  for (int p = 0; p < 2; p++) {
    int c = cl + p * 32;
    int s = sq * 4;
    if (s0 + s < S_) {
      float4 v = *(const float4*)(sp + (size_t)c * S_ + s);
      tile[s + 0][c] = v.x; tile[s + 1][c] = v.y;
      tile[s + 2][c] = v.z; tile[s + 3][c] = v.w;
    }
  }
  __syncthreads();
  int sl = t >> 4, cq = t & 15;
  #pragma unroll
  for (int p = 0; p < 2; p++) {
    int s = sl + p * 16;
    if (s0 + s < S_) {
      us4 v;
      v.x = f2bf(tile[s][cq * 4 + 0]); v.y = f2bf(tile[s][cq * 4 + 1]);
      v.z = f2bf(tile[s][cq * 4 + 2]); v.w = f2bf(tile[s][cq * 4 + 3]);
      *(us4*)(dst + ((size_t)b * S_ + s0 + s) * C_ + c0 + cq * 4) = v;
    }
  }
}

// ---------------- u[b,h] = mean_t v_q[b,t,h] ----------------
__global__ void umean_k(const float* __restrict__ vq, float* __restrict__ u) {
  int b = blockIdx.y;
  int h = blockIdx.x * 256 + threadIdx.x;
  const float* p = vq + (size_t)b * T_ * HID_ + h;
  float s = 0.f;
  #pragma unroll
  for (int t = 0; t < T_; t++) s += p[t * HID_];
  u[(size_t)b * HID_ + h] = s * (1.f / T_);
}

// ---------------- vqt[b,k] = sum_h u[b,h]*w_u[k,h] + b_u[k] ----------------
__global__ void vqt_k(const float* __restrict__ u, const float* __restrict__ wu,
                      const float* __restrict__ bu, float* __restrict__ out) {
  __shared__ float us[32][64];
  __shared__ float ws[64][65];
  int k0 = blockIdx.x * 64, b0 = blockIdx.y * 32;
  int tid = threadIdx.x;
  int kl = tid & 63, bg = tid >> 6;
  float acc[8];
  #pragma unroll
  for (int j = 0; j < 8; j++) acc[j] = 0.f;
  for (int h0 = 0; h0 < HID_; h0 += 64) {
    __syncthreads();
    for (int idx = tid; idx < 32 * 16; idx += 256) {
      int bi = idx >> 4, jj = (idx & 15) * 4;
      *(float4*)&us[bi][jj] = *(const float4*)&u[(size_t)(b0 + bi) * HID_ + h0 + jj];
    }
    for (int idx = tid; idx < 64 * 16; idx += 256) {
      int ki = idx >> 4, jj = (idx & 15) * 4;
      float4 v = *(const float4*)&wu[(size_t)(k0 + ki) * HID_ + h0 + jj];
      ws[ki][jj] = v.x; ws[ki][jj + 1] = v.y; ws[ki][jj + 2] = v.z; ws[ki][jj + 3] = v.w;
    }
    __syncthreads();
    #pragma unroll 8
    for (int h = 0; h < 64; h++) {
      float wv = ws[kl][h];
      #pragma unroll
      for (int j = 0; j < 8; j++) acc[j] += wv * us[bg * 8 + j][h];
    }
  }
  #pragma unroll
  for (int j = 0; j < 8; j++)
    out[(size_t)(b0 + bg * 8 + j) * HID_ + k0 + kl] = acc[j] + bu[k0 + kl];
}

// ---------------- main GEMM: out[s,n] = sum_k A[b,s,k] * W[n,k] ----------------
// M=208 (196 valid) x N=NB per block, BK=32. NTHR = NB*4, wave tile M=208 x N=16
// -> acc 13x f32x4 = 52 AGPR/wave, total regs <=128 -> 4 waves/SIMD.
// l1: NB=128 (512 thr, LDS 21.5 KB, 2 blk/CU). hop: NB=64 (256 thr, +e_lds for the
// vi slice [col][row], LDS 44 KB, 3 blk/CU); e_lds is filled from a_lds during the
// k-iters whose k-range equals this block's n-range (A IS vi for hops) -> epilogue
// reads vi via ds_read_b64 instead of uncoalesced global scalars.
template<int KDIM, int NB, bool IS_HOP>
__global__ __launch_bounds__(NB * 4, 4)
void gemm_k(const __hip_bfloat16* __restrict__ Asrc,
            const __hip_bfloat16* __restrict__ Bw,
            const float* __restrict__ aux,      // l1: bias[1024]; hop: vqt[B][1024]
            __hip_bfloat16* __restrict__ vi,    // l1: output
            float* __restrict__ u) {            // hop: in/out [B][1024]
  constexpr int MS   = 13;
  constexpr int NTHR = NB * 4;
  constexpr int ACH  = 832;                     // A chunks (208 rows x 4)
  constexpr int BCH  = NB * 4;                  // B chunks
  constexpr int AR   = (ACH + NTHR - 1) / NTHR;
  constexpr int NBLK = HID_ / NB;
  constexpr int NBITS = (NB == 128) ? 3 : 4;

  __shared__ short a_lds[ACH * 8];
  __shared__ short b_lds[BCH * 8];
  __shared__ short e_lds[IS_HOP ? NB * 208 : 8];

  const int id = blockIdx.x;
  const int b  = (id & 3) | ((id >> (2 + NBITS)) << 2);
  const int n0 = ((id >> 2) & (NBLK - 1)) * NB;
  const int tid  = threadIdx.x;
  const int wv   = tid >> 6;
  const int lane = tid & 63;
  const int ln   = lane & 15;
  const int quad = lane >> 4;
  const int qsw  = quad ^ ((ln >> 1) & 3);

  const short* Ab = (const short*)(Asrc + (size_t)b * S_ * KDIM);
  const short* Bb = (const short*)Bw + (size_t)n0 * KDIM;

  f32x4_t acc[MS] = {};

  for (int k0 = 0; k0 < KDIM; k0 += 32) {
    __syncthreads();
    #pragma unroll
    for (int p = 0; p < AR; p++) {
      int i = tid + p * NTHR;
      if (i < ACH) {
        int m = i >> 2;
        int q = (i & 3) ^ ((i >> 3) & 3);
        int mg = (m < S_) ? m : (S_ - 1);
        gl_lds16(Ab + (size_t)mg * KDIM + k0 + q * 8, &a_lds[i * 8]);
      }
    }
    {
      int i = tid;                               // BCH == NTHR for both configs
      int n = i >> 2;
      int q = (i & 3) ^ ((i >> 3) & 3);
      gl_lds16(Bb + (size_t)n * KDIM + k0 + q * 8, &b_lds[i * 8]);
    }
    __syncthreads();
    if (IS_HOP) {                                // vi slice passes through: save it
      unsigned w = (unsigned)(k0 - n0);
      if (w < (unsigned)NB) {
        #pragma unroll
        for (int p = 0; p < AR; p++) {
          int i = tid + p * NTHR;
          if (i < ACH) {
            int m = i >> 2;
            int q = (i & 3) ^ ((i >> 3) & 3);
            s16x8 v = *(s16x8*)&a_lds[i * 8];
            int cb = (int)w + q * 8;
            #pragma unroll
            for (int t = 0; t < 8; t++) e_lds[(cb + t) * 208 + m] = v[t];
          }
        }
      }
    }
    s16x8 bf = *(s16x8*)&b_lds[((wv * 16 + ln) * 4 + qsw) * 8];
    #pragma unroll
    for (int ms = 0; ms < MS; ms++) {
      s16x8 af = *(s16x8*)&a_lds[((ms * 16 + ln) * 4 + qsw) * 8];
      acc[ms] = __builtin_amdgcn_mfma_f32_16x16x32_bf16(af, bf, acc[ms], 0, 0, 0);
    }
  }

  // C/D layout: col = lane&15, row = quad*4 + reg
  const int col0 = n0 + wv * 16 + ln;
  if (!IS_HOP) {
    float bias0 = aux[col0];
    #pragma unroll
    for (int ms = 0; ms < MS; ms++) {
      #pragma unroll
      for (int r = 0; r < 4; r++) {
        int row = ms * 16 + quad * 4 + r;
        if (row < S_)
          vi[((size_t)b * S_ + row) * HID_ + col0] =
              __float2bfloat16(fast_tanh(acc[ms][r] + bias0));
      }
    }
  } else {
    __syncthreads();                             // e_lds from last window iter
    float vq0 = aux[(size_t)b * HID_ + col0];
    float mx0 = -1e30f;
    #pragma unroll
    for (int ms = 0; ms < MS; ms++) {
      #pragma unroll
      for (int r = 0; r < 4; r++) {
        int row = ms * 16 + quad * 4 + r;
        float v0 = (row < S_) ? fast_tanh(acc[ms][r] + vq0) : -1e30f;
        acc[ms][r] = v0;
        mx0 = fmaxf(mx0, v0);
      }
    }
    mx0 = fmaxf(mx0, __shfl_xor(mx0, 16));
    mx0 = fmaxf(mx0, __shfl_xor(mx0, 32));
    float den0 = 0.f, num0 = 0.f;
    const int cl = wv * 16 + ln;                 // local col in e_lds
    #pragma unroll
    for (int ms = 0; ms < MS; ms++) {
      s16x4 vv = *(s16x4*)&e_lds[cl * 208 + ms * 16 + quad * 4];
      #pragma unroll
      for (int r = 0; r < 4; r++) {
        int row = ms * 16 + quad * 4 + r;
        if (row < S_) {
          float e0 = __expf(acc[ms][r] - mx0);
          den0 += e0;
          num0 += e0 * bf2f(vv[r]);
        }
      }
    }
    den0 += __shfl_xor(den0, 16); den0 += __shfl_xor(den0, 32);
    num0 += __shfl_xor(num0, 16); num0 += __shfl_xor(num0, 32);
    if (quad == 0)
      u[(size_t)b * HID_ + col0] += num0 / den0;
  }
}

extern "C" void kernel_launch(void* const* d_in, const int* in_sizes, int n_in,
                              void* d_out, int out_size, void* d_ws, size_t ws_size,
                              hipStream_t stream) {
  const float* v_i   = (const float*)d_in[0];
  const float* v_q   = (const float*)d_in[1];
  const float* l1_w  = (const float*)d_in[2];
  const float* l1_b  = (const float*)d_in[3];
  const float* w_vi0 = (const float*)d_in[4];
  const float* w_u0  = (const float*)d_in[5];
  const float* b_u0  = (const float*)d_in[6];
  const float* w_vi1 = (const float*)d_in[7];
  const float* w_u1  = (const float*)d_in[8];
  const float* b_u1  = (const float*)d_in[9];
  float* u = (float*)d_out;

  __hip_bfloat16* viT  = (__hip_bfloat16*)d_ws;                    // [B][S][C]
  __hip_bfloat16* vi   = viT + (size_t)B_ * S_ * C_;               // [B][S][HID]
  float*          vqt  = (float*)(vi + (size_t)B_ * S_ * HID_);    // [B][HID]
  __hip_bfloat16* l1wb = (__hip_bfloat16*)(vqt + (size_t)B_ * HID_);
  __hip_bfloat16* wv0b = l1wb + (size_t)HID_ * C_;
  __hip_bfloat16* wv1b = wv0b + (size_t)HID_ * HID_;

  cvt_k<<<dim3((HID_ * C_) / 1024), 256, 0, stream>>>(l1_w, l1wb, HID_ * C_);
  cvt_k<<<dim3((HID_ * HID_) / 1024), 256, 0, stream>>>(w_vi0, wv0b, HID_ * HID_);
  cvt_k<<<dim3((HID_ * HID_) / 1024), 256, 0, stream>>>(w_vi1, wv1b, HID_ * HID_);
  transpose_k<<<dim3(C_ / 64, 7, B_), 256, 0, stream>>>(v_i, viT);
  umean_k<<<dim3(HID_ / 256, B_), 256, 0, stream>>>(v_q, u);

  // l1: NB=128, 512 threads, grid 4*8*32 = 1024
  gemm_k<C_, 128, false><<<dim3(1024), 512, 0, stream>>>(viT, l1wb, l1_b, vi, nullptr);

  // hops: NB=64, 256 threads, grid 4*16*32 = 2048
  vqt_k<<<dim3(16, 4), 256, 0, stream>>>(u, w_u0, b_u0, vqt);
  gemm_k<HID_, 64, true><<<dim3(2048), 256, 0, stream>>>(vi, wv0b, vqt, nullptr, u);

  vqt_k<<<dim3(16, 4), 256, 0, stream>>>(u, w_u1, b_u1, vqt);
  gemm_k<HID_, 64, true><<<dim3(2048), 256, 0, stream>>>(vi, wv1b, vqt, nullptr, u);
}